// Round 12
// baseline (10544.415 us; speedup 1.0000x reference)
//
#include <hip/hip_runtime.h>

#define TS   2048
#define H    500
#define E    300
#define HP   512
#define NCLS 20
#define NL0  250       // L0 blocks: 1 wave, 2 units (8 gate rows)
#define NL1  500       // L1 blocks: 1 wave, 1 unit (4 gate rows)

typedef float v2f __attribute__((ext_vector_type(2)));
typedef float v4f __attribute__((ext_vector_type(4)));

__device__ __forceinline__ float tanh_(float x){ return 2.0f/(1.0f+__expf(-2.0f*x)) - 1.0f; }
__device__ __forceinline__ v4f v4z(){ v4f r; r.x=0.f; r.y=0.f; r.z=0.f; r.w=0.f; return r; }
__device__ __forceinline__ v4f v4sub(v4f v, float s){ v4f r; r.x=v.x-s; r.y=v.y-s; r.z=v.z-s; r.w=v.w-s; return r; }
__device__ __forceinline__ bool nz4(v4f v){ return v.x!=0.f && v.y!=0.f && v.z!=0.f && v.w!=0.f; }
__device__ __forceinline__ float dot4(v4f w, v4f x){ return w.x*x.x + w.y*x.y + w.z*x.z + w.w*x.w; }
__device__ __forceinline__ float sum4(v4f v){ return v.x+v.y+v.z+v.w; }

// device-coherent polls (LLC is the only cross-XCD coherence point)
__device__ __forceinline__ void poll2(const float* p0, const float* p1, v4f& a, v4f& b){
    asm volatile("global_load_dwordx4 %0, %2, off sc0 sc1\n\t"
                 "global_load_dwordx4 %1, %3, off sc0 sc1\n\t"
                 "s_waitcnt vmcnt(0)"
                 : "=&v"(a), "=&v"(b) : "v"(p0), "v"(p1));
}
__device__ __forceinline__ void poll4(const float* p0, const float* p1,
                                      const float* p2, const float* p3,
                                      v4f& a, v4f& b, v4f& c, v4f& d){
    asm volatile("global_load_dwordx4 %0, %4, off sc0 sc1\n\t"
                 "global_load_dwordx4 %1, %5, off sc0 sc1\n\t"
                 "global_load_dwordx4 %2, %6, off sc0 sc1\n\t"
                 "global_load_dwordx4 %3, %7, off sc0 sc1\n\t"
                 "s_waitcnt vmcnt(0)"
                 : "=&v"(a), "=&v"(b), "=&v"(c), "=&v"(d)
                 : "v"(p0), "v"(p1), "v"(p2), "v"(p3));
}
__device__ __forceinline__ void store1_cc(float* p, float v){
    asm volatile("global_store_dword %0, %1, off sc0 sc1" :: "v"(p), "v"(v));
}
__device__ __forceinline__ void store2_cc(float* p, v2f v){
    asm volatile("global_store_dwordx2 %0, %1, off sc0 sc1" :: "v"(p), "v"(v));
}

// h buffers t-indexed, write-once; 0 == not written (real values are h+2 in (1,3)).
__global__ __launch_bounds__(256) void lstm_init(float* hs) {
    int i = blockIdx.x*256 + threadIdx.x;
    const int NH4 = (TS+1)*HP/4;
    v4f b2; b2.x=2.f; b2.y=2.f; b2.z=2.f; b2.w=2.f;
    bool seed = (i < H/4) || (i >= NH4 && i < NH4 + H/4);   // t=0 rows
    ((v4f*)hs)[i] = seed ? b2 : v4z();
}

// reduce-scatter 8 rows over 64 lanes -> lane L holds row 4b0+2b1+b2  [R7-verified]
__device__ __forceinline__ float reduce8(float* acc, int lane){
    float v4a[4];
    { const bool b = lane & 1;
      #pragma unroll
      for (int i = 0; i < 4; ++i){
        float keep = b ? acc[4+i] : acc[i];
        float send = b ? acc[i]   : acc[4+i];
        v4a[i] = keep + __shfl_xor(send, 1, 64); } }
    float v2a[2];
    { const bool b = lane & 2;
      #pragma unroll
      for (int i = 0; i < 2; ++i){
        float keep = b ? v4a[2+i] : v4a[i];
        float send = b ? v4a[i]   : v4a[2+i];
        v2a[i] = keep + __shfl_xor(send, 2, 64); } }
    float v1;
    { const bool b = lane & 4;
      float keep = b ? v2a[1] : v2a[0];
      float send = b ? v2a[0] : v2a[1];
      v1 = keep + __shfl_xor(send, 4, 64); }
    v1 += __shfl_xor(v1, 8, 64);
    v1 += __shfl_xor(v1, 16, 64);
    v1 += __shfl_xor(v1, 32, 64);
    return v1;
}

// reduce-scatter 4 rows over 64 lanes -> lane L holds row 2b0+b1
__device__ __forceinline__ float reduce4(float* acc, int lane){
    float v2a[2];
    { const bool b = lane & 1;
      #pragma unroll
      for (int i = 0; i < 2; ++i){
        float keep = b ? acc[2+i] : acc[i];
        float send = b ? acc[i]   : acc[2+i];
        v2a[i] = keep + __shfl_xor(send, 1, 64); } }
    float v1;
    { const bool b = lane & 2;
      float keep = b ? v2a[1] : v2a[0];
      float send = b ? v2a[0] : v2a[1];
      v1 = keep + __shfl_xor(send, 2, 64); }
    v1 += __shfl_xor(v1, 4, 64);
    v1 += __shfl_xor(v1, 8, 64);
    v1 += __shfl_xor(v1, 16, 64);
    v1 += __shfl_xor(v1, 32, 64);
    return v1;
}

// L0: lane's gate g = 2*b1+b2. xor4 -> g^1, xor2 -> g^2, xor6 -> g^3  [R7-verified]
__device__ __forceinline__ float gates8(float x, int g, float& cs){
    const bool isG = (g == 2);
    float a = 1.f/(1.f + __expf(isG ? -2.f*x : -x));
    float act = isG ? 2.f*a - 1.f : a;
    float t1 = __shfl_xor(act, 4, 64);   // g^1
    float t2 = __shfl_xor(act, 2, 64);   // g^2
    float t3 = __shfl_xor(act, 6, 64);   // g^3
    float gi = (g==0)?act:(g==1)?t1:(g==2)?t2:t3;
    float gf = (g==1)?act:(g==0)?t1:(g==3)?t2:t3;
    float gg = (g==2)?act:(g==3)?t1:(g==0)?t2:t3;
    float go = (g==3)?act:(g==2)?t1:(g==1)?t2:t3;
    cs = gf*cs + gi*gg;
    return go * tanh_(cs);
}

// L1: lane's gate g = 2*b0+b1. xor2 -> g^1, xor1 -> g^2, xor3 -> g^3
__device__ __forceinline__ float gates4(float x, int g, float& cs){
    const bool isG = (g == 2);
    float a = 1.f/(1.f + __expf(isG ? -2.f*x : -x));
    float act = isG ? 2.f*a - 1.f : a;
    float t1 = __shfl_xor(act, 2, 64);   // g^1
    float t2 = __shfl_xor(act, 1, 64);   // g^2
    float t3 = __shfl_xor(act, 3, 64);   // g^3
    float gi = (g==0)?act:(g==1)?t1:(g==2)?t2:t3;
    float gf = (g==1)?act:(g==0)?t1:(g==3)?t2:t3;
    float gg = (g==2)?act:(g==3)?t1:(g==0)?t2:t3;
    float go = (g==3)?act:(g==2)?t1:(g==1)?t2:t3;
    cs = gf*cs + gi*gg;
    return go * tanh_(cs);
}

__launch_bounds__(64, 2)
__global__ void lstm_main(
    const int* __restrict__ seq, const float* __restrict__ emb,
    const float* __restrict__ Wih0, const float* __restrict__ Whh0,
    const float* __restrict__ bih0, const float* __restrict__ bhh0,
    const float* __restrict__ Wih1, const float* __restrict__ Whh1,
    const float* __restrict__ bih1, const float* __restrict__ bhh1,
    const float* __restrict__ fcW, const float* __restrict__ fcb,
    float* __restrict__ out,
    float* h0s, float* h1s)
{
    const int blk = blockIdx.x;
    const int j   = (int)(threadIdx.x & 63);
    const int b0 = j&1, b1=(j>>1)&1, b2=(j>>2)&1;
    const int cA = 4*j, cB = 256 + 4*j;
    const bool hasB = (cB + 4 <= H);     // j <= 60

    if (blk < NL0) {
        // ========== layer 0: 1 wave, 2 units, 8 rows, no barriers ==========
        const int u0 = 2*blk;
        const int unit = b0, gate = 2*b1 + b2;
        const int Rlane = gate*H + u0 + unit;
        const bool hasXB = (cB + 4 <= E);          // j <= 10

        v4f w0[8], w1[8];
        float rs[8];
        #pragma unroll
        for (int r = 0; r < 8; ++r) {
            const int R_ = (r&3)*H + u0 + (r>>2);
            const float* wh = Whh0 + (size_t)R_*H;
            w0[r] = *(const v4f*)(wh + cA);
            w1[r] = hasB ? *(const v4f*)(wh + cB) : v4z();
            rs[r] = sum4(w0[r]) + sum4(w1[r]);
        }
        // folds bias + the (h+2)-encoding correction (-2*sum(Whh row))
        const float off = bih0[Rlane] + bhh0[Rlane] - 2.f*reduce8(rs, j);

        float cs = 0.f;
        v4f xA = *(const v4f*)(emb + (size_t)seq[0]*E + cA);
        v4f xB = hasXB ? *(const v4f*)(emb + (size_t)seq[0]*E + cB) : v4z();

        for (int t = 1; t <= TS; ++t) {
            // prefetch next x row (consumed next iteration)
            v4f xnA = xA, xnB = xB;
            if (t < TS) {
                const float* er = emb + (size_t)seq[t]*E;
                xnA = *(const v4f*)(er + cA);
                if (hasXB) xnB = *(const v4f*)(er + cB);
            }
            // x-projection partials; Wih0 streamed from L1$ each step.
            // in-loop pointer pin DEFEATS hoisting (keeps VGPR pressure low).
            const float* wip = Wih0;
            asm volatile("" : "+v"(wip));
            float acc[8];
            #pragma unroll
            for (int r = 0; r < 8; ++r) {
                const int R_ = (r&3)*H + u0 + (r>>2);
                const float* wr = wip + (size_t)R_*E;
                v4f wxa = *(const v4f*)(wr + cA);
                acc[r] = dot4(wxa, xA);
                if (hasXB) {
                    v4f wxb = *(const v4f*)(wr + cB);
                    acc[r] += dot4(wxb, xB);
                }
            }
            // rendezvous: h0(t-1)
            const float* hp = h0s + (size_t)(t-1)*HP;
            v4f A, B; bool ok = false;
            while (!__all(ok)) {
                if (!ok) {
                    poll2(hp + cA, hp + cB, A, B);
                    ok = nz4(A) && (!hasB || nz4(B));
                }
            }
            #pragma unroll
            for (int r = 0; r < 8; ++r)
                acc[r] += dot4(w0[r], A) + dot4(w1[r], B);   // raw (h+2); w1=0 masks pad
            float v = reduce8(acc, j) + off;
            float hval = gates8(v, gate, cs);
            float hother = __shfl_xor(hval, 1, 64);          // partner unit's h
            if (j == 0) {
                v2f hv2; hv2.x = hval + 2.f; hv2.y = hother + 2.f;
                store2_cc(h0s + (size_t)t*HP + u0, hv2);
            }
            xA = xnA; xB = xnB;
        }
    } else {
        // ========== layer 1: 1 wave, 1 unit, 4 rows, no barriers ==========
        const int u = blk - NL0;
        const int gl = 2*b0 + b1;                   // lane's gate (reduce4 layout)

        v4f wa[4], wb[4], wc[4], wd[4];
        float rs[4];
        #pragma unroll
        for (int r = 0; r < 4; ++r) {               // r = gate
            const int R_ = r*H + u;
            const float* wi = Wih1 + (size_t)R_*H;
            const float* wh = Whh1 + (size_t)R_*H;
            wa[r] = *(const v4f*)(wi + cA);
            wb[r] = hasB ? *(const v4f*)(wi + cB) : v4z();
            wc[r] = *(const v4f*)(wh + cA);
            wd[r] = hasB ? *(const v4f*)(wh + cB) : v4z();
            rs[r] = sum4(wa[r]) + sum4(wb[r]) + sum4(wc[r]) + sum4(wd[r]);
        }
        const float off = bih1[gl*H + u] + bhh1[gl*H + u] - 2.f*reduce4(rs, j);
        float cs = 0.f;

        for (int t = 1; t <= TS; ++t) {
            const float* pa = h0s + (size_t)t*HP;       // h0(t)
            const float* pb = h1s + (size_t)(t-1)*HP;   // h1(t-1)
            v4f A, B, C, D; bool ok = false;
            while (!__all(ok)) {
                if (!ok) {
                    poll4(pa+cA, pa+cB, pb+cA, pb+cB, A, B, C, D);
                    ok = nz4(A) && nz4(C) && (!hasB || (nz4(B) && nz4(D)));
                }
            }
            float acc[4];
            #pragma unroll
            for (int r = 0; r < 4; ++r)
                acc[r] = dot4(wa[r], A) + dot4(wb[r], B)
                       + dot4(wc[r], C) + dot4(wd[r], D);
            float v = reduce4(acc, j) + off;
            float hval = gates4(v, gl, cs);
            if (j == 0)
                store1_cc(h1s + (size_t)t*HP + u, hval + 2.f);
        }

        if (u == 0) {
            // final FC on h1(T)
            const float* hT = h1s + (size_t)TS*HP;
            v4f A, B; bool ok = false;
            while (!__all(ok)) {
                if (!ok) {
                    poll2(hT + cA, hT + cB, A, B);
                    ok = nz4(A) && (!hasB || nz4(B));
                }
            }
            v4f v0 = v4sub(A, 2.f);
            v4f v1 = hasB ? v4sub(B, 2.f) : v4z();
            #pragma unroll 4
            for (int r = 0; r < NCLS; ++r) {
                const float* wr = fcW + (size_t)r*H;
                v4f fa = *(const v4f*)(wr + cA);
                v4f fb = hasB ? *(const v4f*)(wr + cB) : v4z();
                float a = dot4(fa, v0) + dot4(fb, v1);
                #pragma unroll
                for (int m = 32; m >= 1; m >>= 1) a += __shfl_xor(a, m, 64);
                if (j == 0) out[r] = a + fcb[r];
            }
        }
    }
}

extern "C" void kernel_launch(void* const* d_in, const int* in_sizes, int n_in,
                              void* d_out, int out_size, void* d_ws, size_t ws_size,
                              hipStream_t stream)
{
    const int*   seq  = (const int*)d_in[0];
    const float* emb  = (const float*)d_in[1];
    const float* Wih0 = (const float*)d_in[2];
    const float* Whh0 = (const float*)d_in[3];
    const float* bih0 = (const float*)d_in[4];
    const float* bhh0 = (const float*)d_in[5];
    const float* Wih1 = (const float*)d_in[6];
    const float* Whh1 = (const float*)d_in[7];
    const float* bih1 = (const float*)d_in[8];
    const float* bhh1 = (const float*)d_in[9];
    const float* fcW  = (const float*)d_in[10];
    const float* fcb  = (const float*)d_in[11];
    float* out = (float*)d_out;

    float* h0s = (float*)d_ws;
    float* h1s = h0s + (size_t)(TS+1)*HP;

    // zero/seed both h buffers: 2*2049*512 floats = 524544 v4f = 2049 blocks x 256 thr
    hipLaunchKernelGGL(lstm_init, dim3(2049), dim3(256), 0, stream, h0s);
    hipLaunchKernelGGL(lstm_main, dim3(NL0 + NL1), dim3(64), 0, stream,
                       seq, emb, Wih0, Whh0, bih0, bhh0, Wih1, Whh1, bih1, bhh1,
                       fcW, fcb, out, h0s, h1s);
}